// Round 5
// baseline (129.090 us; speedup 1.0000x reference)
//
#include <hip/hip_runtime.h>
#include <hip/hip_bf16.h>
#include <math.h>
#include <stdint.h>

// Problem constants: B=4, C=512, T=2048, H=8, dh=64, G=32
#define Bb 4
#define Cc 512
#define Tt 2048
#define Hh 8

typedef __attribute__((ext_vector_type(8))) short short8;   // 8 bf16 (4 VGPR) MFMA operand
typedef __attribute__((ext_vector_type(4))) float f32x4;    // MFMA accumulator
typedef __attribute__((ext_vector_type(8))) unsigned short u16x8;

__device__ __forceinline__ unsigned short f2bf(float f) {
  __hip_bfloat16 h = __float2bfloat16(f);
  unsigned short u;
  __builtin_memcpy(&u, &h, 2);
  return u;
}
__device__ __forceinline__ float bf2f(unsigned short u) {
  union { uint32_t i; float f; } v;
  v.i = (uint32_t)u << 16;
  return v.f;
}

__device__ __forceinline__ void async16(const void* g, void* l) {
  __builtin_amdgcn_global_load_lds(
      (const __attribute__((address_space(1))) uint32_t*)g,
      (__attribute__((address_space(3))) uint32_t*)l, 16, 0, 0);
}

// ---------------------------------------------------------------------------
// K1: per-(b,group) mean/rstd.
// ---------------------------------------------------------------------------
__global__ __launch_bounds__(256) void gn_stats(const float* __restrict__ x,
                                                float* __restrict__ stats) {
  const int blk = blockIdx.x;
  const size_t base = (size_t)blk * 16 * Tt;
  const int N = 16 * Tt;
  const int tid = threadIdx.x;
  float s = 0.f, ss = 0.f;
  for (int i = tid * 4; i < N; i += 1024) {
    const float4 v = *(const float4*)(x + base + i);
    s += v.x + v.y + v.z + v.w;
    ss += v.x * v.x + v.y * v.y + v.z * v.z + v.w * v.w;
  }
#pragma unroll
  for (int off = 32; off >= 1; off >>= 1) {
    s += __shfl_down(s, off);
    ss += __shfl_down(ss, off);
  }
  __shared__ float rs[4], rss[4];
  const int wid = tid >> 6;
  if ((tid & 63) == 0) { rs[wid] = s; rss[wid] = ss; }
  __syncthreads();
  if (tid == 0) {
    const float a = rs[0] + rs[1] + rs[2] + rs[3];
    const float c = rss[0] + rss[1] + rss[2] + rss[3];
    const float mean = a / (float)N;
    const float var = c / (float)N - mean * mean;
    stats[blk * 2] = mean;
    stats[blk * 2 + 1] = rsqrtf(var + 1e-5f);
  }
}

// ---------------------------------------------------------------------------
// K2: normalize + convert + transpose: x fp32 [b][c][t] -> hT bf16 [b][t][c].
// ---------------------------------------------------------------------------
__global__ __launch_bounds__(256) void norm_trans(const float* __restrict__ x,
                                                  const float* __restrict__ stats,
                                                  const float* __restrict__ gamma,
                                                  const float* __restrict__ beta,
                                                  unsigned short* __restrict__ hT) {
  __shared__ unsigned short Tl[64][72];
  const int tid = threadIdx.x;
  const int b = blockIdx.z, c0 = blockIdx.y * 64, t0 = blockIdx.x * 64;
  const int cl = tid >> 2, j16 = (tid & 3) * 16;
  const int c = c0 + cl;
  const int grp = c >> 4;
  const float mean = stats[((size_t)b * 32 + grp) * 2];
  const float rstd = stats[((size_t)b * 32 + grp) * 2 + 1];
  const float ga = gamma[c] * rstd;
  const float be = beta[c] - mean * ga;
  const float* src = x + ((size_t)b * Cc + c) * Tt + t0 + j16;
#pragma unroll
  for (int q = 0; q < 4; ++q) {
    const float4 v = *(const float4*)(src + q * 4);
    Tl[j16 + q * 4 + 0][cl] = f2bf(v.x * ga + be);
    Tl[j16 + q * 4 + 1][cl] = f2bf(v.y * ga + be);
    Tl[j16 + q * 4 + 2][cl] = f2bf(v.z * ga + be);
    Tl[j16 + q * 4 + 3][cl] = f2bf(v.w * ga + be);
  }
  __syncthreads();
  const int tl = tid >> 2, i16 = (tid & 3) * 16;
  unsigned short* dst = hT + ((size_t)b * Tt + t0 + tl) * Cc + c0 + i16;
  *(u16x8*)dst = *(const u16x8*)&Tl[tl][i16];
  *(u16x8*)(dst + 8) = *(const u16x8*)&Tl[tl][i16 + 8];
}

// ---------------------------------------------------------------------------
// K3: fp32 -> bf16 convert (weights).
// ---------------------------------------------------------------------------
__global__ __launch_bounds__(256) void cvt_bf16(const float* __restrict__ in,
                                                unsigned short* __restrict__ out, int n4) {
  const int i = blockIdx.x * 256 + threadIdx.x;
  if (i < n4) {
    const float4 v = *(const float4*)(in + (size_t)i * 4);
    ushort4 o;
    o.x = f2bf(v.x); o.y = f2bf(v.y); o.z = f2bf(v.z); o.w = f2bf(v.w);
    *(ushort4*)(out + (size_t)i * 4) = o;
  }
}

// ---------------------------------------------------------------------------
// K4: bf16 transpose 64x64: qkv [b][3C][t] (Q,K) -> qkt [(bh*2+w)][t][64].
// Q (which==0) pre-scaled by 0.125*log2(e) -> scores land in log2 domain.
// ---------------------------------------------------------------------------
__global__ __launch_bounds__(256) void qk_trans(const unsigned short* __restrict__ qkv,
                                                unsigned short* __restrict__ qkt) {
  __shared__ unsigned short Tl[64][72];
  const int tid = threadIdx.x;
  const int t0 = blockIdx.x * 64;
  const int bhw = blockIdx.y;  // (b*8+h)*2 + which
  const int b = bhw >> 4, hw = bhw & 15;
  const int h = hw >> 1, which = hw & 1;
  const unsigned short* src =
      qkv + ((size_t)b * (3 * Cc) + h * 192 + which * 64) * Tt + t0;
  const int dl = tid >> 2, j16 = (tid & 3) * 16;
  u16x8 a0 = *(const u16x8*)(src + (size_t)dl * Tt + j16);
  u16x8 a1 = *(const u16x8*)(src + (size_t)dl * Tt + j16 + 8);
  if (which == 0) {
    const float qs = 0.125f * 1.44269504f;
#pragma unroll
    for (int q = 0; q < 8; ++q) {
      a0[q] = f2bf(bf2f(a0[q]) * qs);
      a1[q] = f2bf(bf2f(a1[q]) * qs);
    }
  }
#pragma unroll
  for (int q = 0; q < 8; ++q) Tl[j16 + q][dl] = a0[q];
#pragma unroll
  for (int q = 0; q < 8; ++q) Tl[j16 + 8 + q][dl] = a1[q];
  __syncthreads();
  const int tl = tid >> 2, i16 = (tid & 3) * 16;
  unsigned short* dst = qkt + ((size_t)bhw * Tt + t0 + tl) * 64 + i16;
  *(u16x8*)dst = *(const u16x8*)&Tl[tl][i16];
  *(u16x8*)(dst + 8) = *(const u16x8*)&Tl[tl][i16 + 8];
}

// ---------------------------------------------------------------------------
// K5: bf16 MFMA GEMM (m97 structure), BM x 128 tile, BK=32, 4 waves.
// BM=128: waves 2x2 of 64x64. BM=64: waves 2x2 of 32x64 (2x blocks -> 2/CU
// for the small proj GEMM). MODE 0: bf16 out. MODE 1: fp32 out + residual.
// ---------------------------------------------------------------------------
template <int MODE, int BM>
__global__ __launch_bounds__(256) void gemm_mfma(const unsigned short* __restrict__ A,
                                                 const unsigned short* __restrict__ Bt,
                                                 const float* __restrict__ bias,
                                                 const float* __restrict__ res,
                                                 unsigned short* __restrict__ outb,
                                                 float* __restrict__ outf, int M) {
  constexpr int NA = BM / 32;  // A-frags per wave
  __shared__ unsigned short Al[BM * 32];
  __shared__ unsigned short Bl[128 * 32];
  const int tid = threadIdx.x;
  const int n0 = blockIdx.x * 128, m0 = blockIdx.y * BM;
  const size_t z = blockIdx.z;
  const int l = tid & 63, il = l & 15, g = l >> 4;
  const int w = tid >> 6;
  const int wm = (w >> 1) * (BM / 2), wn = (w & 1) * 64;

  const unsigned short* Bz = Bt + z * (size_t)Tt * Cc;
  const unsigned short* Ap = A + (size_t)(m0 + (tid >> 2)) * Cc + (tid & 3) * 8;
  const unsigned short* Bp = Bz + (size_t)(n0 + (tid >> 2)) * Cc + (tid & 3) * 8;
  char* ldsA = (char*)Al + w * 1024;
  char* ldsB = (char*)Bl + w * 1024;

  f32x4 acc[NA][4] = {};
  for (int k0 = 0; k0 < Cc; k0 += 32) {
    async16(Ap + k0, ldsA);
    if (BM == 128) async16(Ap + (size_t)64 * Cc + k0, ldsA + 4096);
    async16(Bp + k0, ldsB);
    async16(Bp + (size_t)64 * Cc + k0, ldsB + 4096);
    __syncthreads();
    short8 af[NA], bf[4];
#pragma unroll
    for (int i = 0; i < NA; ++i)
      af[i] = *(const short8*)(Al + (wm + i * 16 + il) * 32 + g * 8);
#pragma unroll
    for (int j = 0; j < 4; ++j)
      bf[j] = *(const short8*)(Bl + (wn + j * 16 + il) * 32 + g * 8);
    __builtin_amdgcn_s_setprio(1);
#pragma unroll
    for (int i = 0; i < NA; ++i)
#pragma unroll
      for (int j = 0; j < 4; ++j)
        acc[i][j] = __builtin_amdgcn_mfma_f32_16x16x32_bf16(af[i], bf[j], acc[i][j], 0, 0, 0);
    __builtin_amdgcn_s_setprio(0);
    __syncthreads();
  }

#pragma unroll
  for (int i = 0; i < NA; ++i) {
#pragma unroll
    for (int r = 0; r < 4; ++r) {
      const int m = m0 + wm + i * 16 + 4 * g + r;
      const float bv = bias[m];
#pragma unroll
      for (int j = 0; j < 4; ++j) {
        const int n = n0 + wn + j * 16 + il;
        const float v = acc[i][j][r] + bv;
        const size_t idx = (z * (size_t)M + m) * Tt + n;
        if (MODE == 0) {
          outb[idx] = f2bf(v);
        } else {
          outf[idx] = v + res[idx];
        }
      }
    }
  }
}

// ---------------------------------------------------------------------------
// K6: MFMA flash attention v4.
// Same structure as v3 (4 waves, QBLK=64, KVBLK=64, dbuf global_load_lds with
// pre-swizzled source, in-register P via cvt_pk+permlane) with three VALU
// cuts:
//  (a) accs C-init = -m_run  -> skip-path exp2 needs no subtract;
//  (b) m_run is WAVE-UNIFORM (defer-max THR=8 log2 units bounds p<=256;
//      under-max rows only lose exponent headroom, safe in fp32/bf16);
//  (c) l accumulated by MFMA with an all-ones B operand (acc_l[r] is exactly
//      the row-l the epilogue needs; kills rsum adds + all l shuffles).
// ---------------------------------------------------------------------------
__global__ __launch_bounds__(256, 4) void attn_mfma4(const unsigned short* __restrict__ qkt,
                                                     const unsigned short* __restrict__ qkvc,
                                                     unsigned short* __restrict__ attnoT) {
  __shared__ unsigned short KVs[2][2][64 * 64];  // [buf][K/V][row*64+col] swizzled

  const int tid = threadIdx.x;
  const int w = tid >> 6, l = tid & 63, il = l & 15, g = l >> 4;

  // XCD-aware swizzle (1024 % 8 == 0 -> bijective)
  const int bid = blockIdx.x;
  const int swz = (bid & 7) * 128 + (bid >> 3);
  const int bh = swz >> 5, qt = swz & 31;
  const int b = bh >> 3, h = bh & 7;
  const int q0 = qt * 64;

  const unsigned short* Qb = qkt + (size_t)(bh * 2) * Tt * 64;
  const char* Kb = (const char*)(Qb + (size_t)Tt * 64);
  const char* Vb = (const char*)(qkvc + ((size_t)b * (3 * Cc) + h * 192 + 128) * Tt);

  // Q fragment (B-operand): col q = q0 + w*16 + il, k contiguous
  short8 qf[2];
  {
    const unsigned short* qp = Qb + (size_t)(q0 + w * 16 + il) * 64 + g * 8;
    qf[0] = *(const short8*)qp;
    qf[1] = *(const short8*)(qp + 32);
  }

  // all-ones bf16 fragment for the l-accumulating MFMA
  union { uint32_t u[4]; short8 v; } ones;
  ones.u[0] = ones.u[1] = ones.u[2] = ones.u[3] = 0x3F803F80u;

  float m_run = 0.f;       // wave-uniform, log2 domain
  f32x4 acco[4] = {};      // O[q=4g+r][d=j*16+il]
  f32x4 acc_l = {};        // l[q=4g+r] (all cols identical)

  const int srow = w * 16 + (l >> 3);
  const int scol = ((l & 7) ^ (l >> 3)) << 4;

  auto stage = [&](int buf, int s0) {
    char* kd = (char*)&KVs[buf][0][0] + w * 2048;
    char* vd = (char*)&KVs[buf][1][0] + w * 2048;
    async16(Kb + (size_t)(s0 + srow) * 128 + scol, kd);
    async16(Kb + (size_t)(s0 + srow + 8) * 128 + scol, kd + 1024);
    async16(Vb + (size_t)srow * (Tt * 2) + (size_t)s0 * 2 + scol, vd);
    async16(Vb + (size_t)(srow + 8) * (Tt * 2) + (size_t)s0 * 2 + scol, vd + 1024);
  };

  stage(0, 0);
  __syncthreads();
  int cur = 0;

  const int NT = Tt / 64;
  for (int t = 0; t < NT; ++t) {
    if (t + 1 < NT) stage(cur ^ 1, (t + 1) * 64);
    const unsigned short* Kc = &KVs[cur][0][0];
    const unsigned short* Vc = &KVs[cur][1][0];

    // S^T - m_run = K·Q^T + C(-m_run); lane (il,g): rows s=16i+4g+r, col q=il
    const float nm = -m_run;
    f32x4 accs[4];
#pragma unroll
    for (int i = 0; i < 4; ++i) {
      accs[i][0] = nm; accs[i][1] = nm; accs[i][2] = nm; accs[i][3] = nm;
    }
    __builtin_amdgcn_s_setprio(1);
#pragma unroll
    for (int ks = 0; ks < 2; ++ks) {
#pragma unroll
      for (int i = 0; i < 4; ++i) {
        const short8 kf =
            *(const short8*)(Kc + (i * 16 + il) * 64 + ((((ks << 2) + g) ^ (il & 7)) << 3));
        accs[i] = __builtin_amdgcn_mfma_f32_16x16x32_bf16(kf, qf[ks], accs[i], 0, 0, 0);
      }
    }
    __builtin_amdgcn_s_setprio(0);

    // per-lane max of 16 relative scores
    float pmax = fmaxf(fmaxf(accs[0][0], accs[0][1]), fmaxf(accs[0][2], accs[0][3]));
#pragma unroll
    for (int i = 1; i < 4; ++i)
      pmax = fmaxf(pmax,
                   fmaxf(fmaxf(accs[i][0], accs[i][1]), fmaxf(accs[i][2], accs[i][3])));

    uint32_t pk[4][2];
    if (!__all(pmax <= 8.0f)) {
      // wave-max -> uniform dm; rescale O and l; p = exp2(rel - dm)
      float mx = pmax;
#pragma unroll
      for (int off = 1; off < 64; off <<= 1) mx = fmaxf(mx, __shfl_xor(mx, off));
      const float alpha = __builtin_amdgcn_exp2f(-mx);
      m_run += mx;
#pragma unroll
      for (int j = 0; j < 4; ++j) acco[j] = acco[j] * alpha;
      acc_l = acc_l * alpha;
#pragma unroll
      for (int i = 0; i < 4; ++i) {
        const float p0 = __builtin_amdgcn_exp2f(accs[i][0] - mx);
        const float p1 = __builtin_amdgcn_exp2f(accs[i][1] - mx);
        const float p2 = __builtin_amdgcn_exp2f(accs[i][2] - mx);
        const float p3 = __builtin_amdgcn_exp2f(accs[i][3] - mx);
        asm("v_cvt_pk_bf16_f32 %0, %1, %2" : "=v"(pk[i][0]) : "v"(p0), "v"(p1));
        asm("v_cvt_pk_bf16_f32 %0, %1, %2" : "=v"(pk[i][1]) : "v"(p2), "v"(p3));
      }
    } else {
      // common path: no subtract, no reduction, no rescale
#pragma unroll
      for (int i = 0; i < 4; ++i) {
        const float p0 = __builtin_amdgcn_exp2f(accs[i][0]);
        const float p1 = __builtin_amdgcn_exp2f(accs[i][1]);
        const float p2 = __builtin_amdgcn_exp2f(accs[i][2]);
        const float p3 = __builtin_amdgcn_exp2f(accs[i][3]);
        asm("v_cvt_pk_bf16_f32 %0, %1, %2" : "=v"(pk[i][0]) : "v"(p0), "v"(p1));
        asm("v_cvt_pk_bf16_f32 %0, %1, %2" : "=v"(pk[i][1]) : "v"(p2), "v"(p3));
      }
    }

    // In-register P redistribution to PV A-fragment layout
    uint32_t fr[2][4];
#pragma unroll
    for (int ks = 0; ks < 2; ++ks) {
#pragma unroll
      for (int hh = 0; hh < 2; ++hh) {
        uint32_t a = pk[2 * ks][hh], bq = pk[2 * ks + 1][hh];
        asm("v_permlane32_swap_b32 %0, %1" : "+v"(a), "+v"(bq));
        asm("v_permlane16_swap_b32 %0, %1" : "+v"(a), "+v"(bq));
        fr[ks][hh] = a;
        fr[ks][2 + hh] = bq;
      }
    }

    // O += P·V ; l += P·1
    __builtin_amdgcn_s_setprio(1);
#pragma unroll
    for (int ks = 0; ks < 2; ++ks) {
      union { uint32_t u[4]; short8 v; } fu;
      fu.u[0] = fr[ks][0]; fu.u[1] = fr[ks][1];
      fu.u[2] = fr[ks][2]; fu.u[3] = fr[ks][3];
#pragma unroll
      for (int j = 0; j < 4; ++j) {
        const short8 vf =
            *(const short8*)(Vc + (j * 16 + il) * 64 + ((((ks << 2) + g) ^ (il & 7)) << 3));
        acco[j] = __builtin_amdgcn_mfma_f32_16x16x32_bf16(fu.v, vf, acco[j], 0, 0, 0);
      }
      acc_l = __builtin_amdgcn_mfma_f32_16x16x32_bf16(fu.v, ones.v, acc_l, 0, 0, 0);
    }
    __builtin_amdgcn_s_setprio(0);

    __syncthreads();
    cur ^= 1;
  }

  // Epilogue: acc_l[r] is l for row q=4g+r directly — no shuffles.
#pragma unroll
  for (int r = 0; r < 4; ++r) {
    const float li = 1.f / acc_l[r];
    const int tq = q0 + w * 16 + 4 * g + r;
    unsigned short* d0 = attnoT + ((size_t)b * Tt + tq) * Cc + h * 64 + il;
#pragma unroll
    for (int j = 0; j < 4; ++j) d0[j * 16] = f2bf(acco[j][r] * li);
  }
}

// ---------------------------------------------------------------------------
extern "C" void kernel_launch(void* const* d_in, const int* in_sizes, int n_in,
                              void* d_out, int out_size, void* d_ws, size_t ws_size,
                              hipStream_t stream) {
  const float* x = (const float*)d_in[0];
  const float* gamma = (const float*)d_in[1];
  const float* beta = (const float*)d_in[2];
  const float* w_qkv = (const float*)d_in[3];
  const float* b_qkv = (const float*)d_in[4];
  const float* w_proj = (const float*)d_in[5];
  const float* b_proj = (const float*)d_in[6];
  float* out = (float*)d_out;

  char* p = (char*)d_ws;
  float* stats = (float*)p;                  p += 256 * sizeof(float);
  unsigned short* hT = (unsigned short*)p;   p += (size_t)Bb * Tt * Cc * 2;
  unsigned short* wq = (unsigned short*)p;   p += (size_t)3 * Cc * Cc * 2;
  unsigned short* wp = (unsigned short*)p;   p += (size_t)Cc * Cc * 2;
  unsigned short* qkvc = (unsigned short*)p; p += (size_t)Bb * 3 * Cc * Tt * 2;
  unsigned short* qkt = (unsigned short*)p;  p += (size_t)Bb * Hh * 2 * Tt * 64 * 2;
  unsigned short* attnoT = (unsigned short*)p;

  gn_stats<<<dim3(Bb * 32), 256, 0, stream>>>(x, stats);
  norm_trans<<<dim3(Tt / 64, Cc / 64, Bb), 256, 0, stream>>>(x, stats, gamma, beta, hT);
  cvt_bf16<<<dim3((3 * Cc * Cc / 4 + 255) / 256), 256, 0, stream>>>(w_qkv, wq, 3 * Cc * Cc / 4);
  cvt_bf16<<<dim3((Cc * Cc / 4 + 255) / 256), 256, 0, stream>>>(w_proj, wp, Cc * Cc / 4);
  gemm_mfma<0, 128><<<dim3(Tt / 128, (3 * Cc) / 128, Bb), 256, 0, stream>>>(
      wq, hT, b_qkv, nullptr, qkvc, nullptr, 3 * Cc);
  qk_trans<<<dim3(Tt / 64, Bb * Hh * 2), 256, 0, stream>>>(qkvc, qkt);
  attn_mfma4<<<dim3(1024), 256, 0, stream>>>(qkt, qkvc, attnoT);
  gemm_mfma<1, 64><<<dim3(Tt / 128, Cc / 64, Bb), 256, 0, stream>>>(
      wp, attnoT, b_proj, x, nullptr, out, Cc);
}

// Round 6
// 122.934 us; speedup vs baseline: 1.0501x; 1.0501x over previous
//
#include <hip/hip_runtime.h>
#include <hip/hip_bf16.h>
#include <math.h>
#include <stdint.h>

// Problem constants: B=4, C=512, T=2048, H=8, dh=64, G=32
#define Bb 4
#define Cc 512
#define Tt 2048
#define Hh 8

typedef __attribute__((ext_vector_type(8))) short short8;   // 8 bf16 (4 VGPR) MFMA operand
typedef __attribute__((ext_vector_type(4))) float f32x4;    // MFMA accumulator
typedef __attribute__((ext_vector_type(8))) unsigned short u16x8;

__device__ __forceinline__ unsigned short f2bf(float f) {
  __hip_bfloat16 h = __float2bfloat16(f);
  unsigned short u;
  __builtin_memcpy(&u, &h, 2);
  return u;
}
__device__ __forceinline__ float bf2f(unsigned short u) {
  union { uint32_t i; float f; } v;
  v.i = (uint32_t)u << 16;
  return v.f;
}

__device__ __forceinline__ void async16(const void* g, void* l) {
  __builtin_amdgcn_global_load_lds(
      (const __attribute__((address_space(1))) uint32_t*)g,
      (__attribute__((address_space(3))) uint32_t*)l, 16, 0, 0);
}

// ---------------------------------------------------------------------------
// K1: per-(b,group) mean/rstd.
// ---------------------------------------------------------------------------
__global__ __launch_bounds__(256) void gn_stats(const float* __restrict__ x,
                                                float* __restrict__ stats) {
  const int blk = blockIdx.x;
  const size_t base = (size_t)blk * 16 * Tt;
  const int N = 16 * Tt;
  const int tid = threadIdx.x;
  float s = 0.f, ss = 0.f;
  for (int i = tid * 4; i < N; i += 1024) {
    const float4 v = *(const float4*)(x + base + i);
    s += v.x + v.y + v.z + v.w;
    ss += v.x * v.x + v.y * v.y + v.z * v.z + v.w * v.w;
  }
#pragma unroll
  for (int off = 32; off >= 1; off >>= 1) {
    s += __shfl_down(s, off);
    ss += __shfl_down(ss, off);
  }
  __shared__ float rs[4], rss[4];
  const int wid = tid >> 6;
  if ((tid & 63) == 0) { rs[wid] = s; rss[wid] = ss; }
  __syncthreads();
  if (tid == 0) {
    const float a = rs[0] + rs[1] + rs[2] + rs[3];
    const float c = rss[0] + rss[1] + rss[2] + rss[3];
    const float mean = a / (float)N;
    const float var = c / (float)N - mean * mean;
    stats[blk * 2] = mean;
    stats[blk * 2 + 1] = rsqrtf(var + 1e-5f);
  }
}

// ---------------------------------------------------------------------------
// K2: normalize + convert + transpose: x fp32 [b][c][t] -> hT bf16 [b][t][c].
// ---------------------------------------------------------------------------
__global__ __launch_bounds__(256) void norm_trans(const float* __restrict__ x,
                                                  const float* __restrict__ stats,
                                                  const float* __restrict__ gamma,
                                                  const float* __restrict__ beta,
                                                  unsigned short* __restrict__ hT) {
  __shared__ unsigned short Tl[64][72];
  const int tid = threadIdx.x;
  const int b = blockIdx.z, c0 = blockIdx.y * 64, t0 = blockIdx.x * 64;
  const int cl = tid >> 2, j16 = (tid & 3) * 16;
  const int c = c0 + cl;
  const int grp = c >> 4;
  const float mean = stats[((size_t)b * 32 + grp) * 2];
  const float rstd = stats[((size_t)b * 32 + grp) * 2 + 1];
  const float ga = gamma[c] * rstd;
  const float be = beta[c] - mean * ga;
  const float* src = x + ((size_t)b * Cc + c) * Tt + t0 + j16;
#pragma unroll
  for (int q = 0; q < 4; ++q) {
    const float4 v = *(const float4*)(src + q * 4);
    Tl[j16 + q * 4 + 0][cl] = f2bf(v.x * ga + be);
    Tl[j16 + q * 4 + 1][cl] = f2bf(v.y * ga + be);
    Tl[j16 + q * 4 + 2][cl] = f2bf(v.z * ga + be);
    Tl[j16 + q * 4 + 3][cl] = f2bf(v.w * ga + be);
  }
  __syncthreads();
  const int tl = tid >> 2, i16 = (tid & 3) * 16;
  unsigned short* dst = hT + ((size_t)b * Tt + t0 + tl) * Cc + c0 + i16;
  *(u16x8*)dst = *(const u16x8*)&Tl[tl][i16];
  *(u16x8*)(dst + 8) = *(const u16x8*)&Tl[tl][i16 + 8];
}

// ---------------------------------------------------------------------------
// K3: fp32 -> bf16 convert, both weight tensors in one launch.
// ---------------------------------------------------------------------------
__global__ __launch_bounds__(256) void cvt_bf16_2(const float* __restrict__ a,
                                                  unsigned short* __restrict__ oa, int n4a,
                                                  const float* __restrict__ bsrc,
                                                  unsigned short* __restrict__ ob, int n4b) {
  const int i = blockIdx.x * 256 + threadIdx.x;
  const float* in;
  unsigned short* out;
  int idx;
  if (i < n4a) {
    in = a; out = oa; idx = i;
  } else if (i < n4a + n4b) {
    in = bsrc; out = ob; idx = i - n4a;
  } else {
    return;
  }
  const float4 v = *(const float4*)(in + (size_t)idx * 4);
  ushort4 o;
  o.x = f2bf(v.x); o.y = f2bf(v.y); o.z = f2bf(v.z); o.w = f2bf(v.w);
  *(ushort4*)(out + (size_t)idx * 4) = o;
}

// ---------------------------------------------------------------------------
// K5: bf16 MFMA GEMM (m97 structure), BM x 128 tile, BK=32, 4 waves.
// MODE 0 (QKV): V rows -> channel-major bf16 qkvc; Q/K rows -> token-major
//   qkt[(b*8+h)*2+which][t][64] via per-wave LDS transpose (Q pre-scaled by
//   0.125*log2e so attention scores land in log2 domain). Q/K skip qkvc.
// MODE 1 (proj): fp32 out + residual.
// ---------------------------------------------------------------------------
template <int MODE, int BM>
__global__ __launch_bounds__(256) void gemm_mfma(const unsigned short* __restrict__ A,
                                                 const unsigned short* __restrict__ Bt,
                                                 const float* __restrict__ bias,
                                                 const float* __restrict__ res,
                                                 unsigned short* __restrict__ outb,
                                                 float* __restrict__ outf,
                                                 unsigned short* __restrict__ qkt,
                                                 int M) {
  constexpr int NA = BM / 32;  // A-frags per wave
  __shared__ unsigned short Al[BM * 32];
  __shared__ unsigned short Bl[128 * 32];
  __shared__ unsigned short Sc[(MODE == 0 ? 4 : 1)][32][72];  // transpose scratch
  const int tid = threadIdx.x;
  const int n0 = blockIdx.x * 128, m0 = blockIdx.y * BM;
  const size_t z = blockIdx.z;
  const int l = tid & 63, il = l & 15, g = l >> 4;
  const int w = tid >> 6;
  const int wm = (w >> 1) * (BM / 2), wn = (w & 1) * 64;

  const unsigned short* Bz = Bt + z * (size_t)Tt * Cc;
  const unsigned short* Ap = A + (size_t)(m0 + (tid >> 2)) * Cc + (tid & 3) * 8;
  const unsigned short* Bp = Bz + (size_t)(n0 + (tid >> 2)) * Cc + (tid & 3) * 8;
  char* ldsA = (char*)Al + w * 1024;
  char* ldsB = (char*)Bl + w * 1024;

  f32x4 acc[NA][4] = {};
  for (int k0 = 0; k0 < Cc; k0 += 32) {
    async16(Ap + k0, ldsA);
    if (BM == 128) async16(Ap + (size_t)64 * Cc + k0, ldsA + 4096);
    async16(Bp + k0, ldsB);
    async16(Bp + (size_t)64 * Cc + k0, ldsB + 4096);
    __syncthreads();
    short8 af[NA], bf[4];
#pragma unroll
    for (int i = 0; i < NA; ++i)
      af[i] = *(const short8*)(Al + (wm + i * 16 + il) * 32 + g * 8);
#pragma unroll
    for (int j = 0; j < 4; ++j)
      bf[j] = *(const short8*)(Bl + (wn + j * 16 + il) * 32 + g * 8);
    __builtin_amdgcn_s_setprio(1);
#pragma unroll
    for (int i = 0; i < NA; ++i)
#pragma unroll
      for (int j = 0; j < 4; ++j)
        acc[i][j] = __builtin_amdgcn_mfma_f32_16x16x32_bf16(af[i], bf[j], acc[i][j], 0, 0, 0);
    __builtin_amdgcn_s_setprio(0);
    __syncthreads();
  }

  if (MODE == 1) {
#pragma unroll
    for (int i = 0; i < NA; ++i) {
#pragma unroll
      for (int r = 0; r < 4; ++r) {
        const int m = m0 + wm + i * 16 + 4 * g + r;
        const float bv = bias[m];
#pragma unroll
        for (int j = 0; j < 4; ++j) {
          const int n = n0 + wn + j * 16 + il;
          const size_t idx = (z * (size_t)M + m) * Tt + n;
          outf[idx] = acc[i][j][r] + bv + res[idx];
        }
      }
    }
  } else {
    // wave's 64 rows: r0..r0+63, all one section of one head
    const int r0 = m0 + wm;
    const int sec = (r0 % 192) >> 6;  // 0=Q, 1=K, 2=V
    const int hh = r0 / 192;
    if (sec == 2) {
      // V: channel-major write (attention reads V this way)
#pragma unroll
      for (int i = 0; i < 4; ++i) {
#pragma unroll
        for (int r = 0; r < 4; ++r) {
          const int m = r0 + i * 16 + 4 * g + r;
          const float bv = bias[m];
#pragma unroll
          for (int j = 0; j < 4; ++j) {
            const int n = n0 + wn + j * 16 + il;
            outb[(z * (size_t)M + m) * Tt + n] = f2bf(acc[i][j][r] + bv);
          }
        }
      }
    } else {
      // Q/K: token-major via per-wave LDS scratch (no barriers; wave-private)
      const float qs = (sec == 0) ? 0.125f * 1.44269504f : 1.0f;
      const size_t obase = ((size_t)(z * (Hh * 2)) + hh * 2 + sec) * Tt;
#pragma unroll
      for (int hf = 0; hf < 2; ++hf) {
#pragma unroll
        for (int i = 0; i < 4; ++i) {
          const int mloc = i * 16 + 4 * g;
          const float b0 = bias[r0 + mloc + 0];
          const float b1 = bias[r0 + mloc + 1];
          const float b2 = bias[r0 + mloc + 2];
          const float b3 = bias[r0 + mloc + 3];
#pragma unroll
          for (int j2 = 0; j2 < 2; ++j2) {
            const int j = hf * 2 + j2;
            ushort4 pkk;
            pkk.x = f2bf((acc[i][j][0] + b0) * qs);
            pkk.y = f2bf((acc[i][j][1] + b1) * qs);
            pkk.z = f2bf((acc[i][j][2] + b2) * qs);
            pkk.w = f2bf((acc[i][j][3] + b3) * qs);
            // scratch[n_local][m_local], n = j2*16+il
            *(ushort4*)&Sc[w][j2 * 16 + il][mloc] = pkk;
          }
        }
        asm volatile("s_waitcnt lgkmcnt(0)" ::: "memory");
#pragma unroll
        for (int it = 0; it < 4; ++it) {
          const int row = it * 8 + (l >> 3);   // n-local 0..31
          const int mcol = (l & 7) * 8;
          const u16x8 vv = *(const u16x8*)&Sc[w][row][mcol];
          const int tg = n0 + wn + hf * 32 + row;
          *(u16x8*)(qkt + (obase + tg) * 64 + mcol) = vv;
        }
        asm volatile("s_waitcnt lgkmcnt(0)" ::: "memory");
      }
    }
  }
}

// ---------------------------------------------------------------------------
// K6: MFMA flash attention v5 (T15 pipelined).
// Per iter: [B1 sync] -> {QK(t) ; PV(t-1)} one MFMA-dense region -> [B2 sync]
// -> stage(t+1) -> softmax(t) (covers stage latency; K/V are ~97% L2-hits).
// 4 waves, QBLK=64, KVBLK=64, dbuf global_load_lds w/ pre-swizzled source,
// in-register P via cvt_pk+permlane, wave-uniform defer-max (THR=8, log2),
// l via MFMA ones-trick. Grid 1024 flat, XCD-swizzled.
// ---------------------------------------------------------------------------
__global__ __launch_bounds__(256, 4) void attn_mfma5(const unsigned short* __restrict__ qkt,
                                                     const unsigned short* __restrict__ qkvc,
                                                     unsigned short* __restrict__ attnoT) {
  __shared__ unsigned short KVs[2][2][64 * 64];  // [buf][K/V][row*64+col] swizzled

  const int tid = threadIdx.x;
  const int w = tid >> 6, l = tid & 63, il = l & 15, g = l >> 4;

  const int bid = blockIdx.x;
  const int swz = (bid & 7) * 128 + (bid >> 3);
  const int bh = swz >> 5, qt = swz & 31;
  const int b = bh >> 3, h = bh & 7;
  const int q0 = qt * 64;

  const unsigned short* Qb = qkt + (size_t)(bh * 2) * Tt * 64;
  const char* Kb = (const char*)(Qb + (size_t)Tt * 64);
  const char* Vb = (const char*)(qkvc + ((size_t)b * (3 * Cc) + h * 192 + 128) * Tt);

  short8 qf[2];
  {
    const unsigned short* qp = Qb + (size_t)(q0 + w * 16 + il) * 64 + g * 8;
    qf[0] = *(const short8*)qp;
    qf[1] = *(const short8*)(qp + 32);
  }

  union { uint32_t u[4]; short8 v; } ones;
  ones.u[0] = ones.u[1] = ones.u[2] = ones.u[3] = 0x3F803F80u;

  float m_run = 0.f;       // wave-uniform, log2 domain
  f32x4 acco[4] = {};      // O[q=4g+r][d=j*16+il]
  f32x4 acc_l = {};        // l[q=4g+r]
  uint32_t frP[2][4];      // P(t) as PV A-fragments (carried state)

  const int srow = w * 16 + (l >> 3);
  const int scol = ((l & 7) ^ (l >> 3)) << 4;

  auto stage = [&](int buf, int s0) {
    char* kd = (char*)&KVs[buf][0][0] + w * 2048;
    char* vd = (char*)&KVs[buf][1][0] + w * 2048;
    async16(Kb + (size_t)(s0 + srow) * 128 + scol, kd);
    async16(Kb + (size_t)(s0 + srow + 8) * 128 + scol, kd + 1024);
    async16(Vb + (size_t)srow * (Tt * 2) + (size_t)s0 * 2 + scol, vd);
    async16(Vb + (size_t)(srow + 8) * (Tt * 2) + (size_t)s0 * 2 + scol, vd + 1024);
  };

  f32x4 accs[4];
  auto qk_phase = [&](int buf) {
    const float nm = -m_run;
#pragma unroll
    for (int i = 0; i < 4; ++i) {
      accs[i][0] = nm; accs[i][1] = nm; accs[i][2] = nm; accs[i][3] = nm;
    }
    const unsigned short* Kc = &KVs[buf][0][0];
#pragma unroll
    for (int ks = 0; ks < 2; ++ks) {
#pragma unroll
      for (int i = 0; i < 4; ++i) {
        const short8 kf =
            *(const short8*)(Kc + (i * 16 + il) * 64 + ((((ks << 2) + g) ^ (il & 7)) << 3));
        accs[i] = __builtin_amdgcn_mfma_f32_16x16x32_bf16(kf, qf[ks], accs[i], 0, 0, 0);
      }
    }
  };

  auto pv_phase = [&](int buf) {
    const unsigned short* Vc = &KVs[buf][1][0];
#pragma unroll
    for (int ks = 0; ks < 2; ++ks) {
      union { uint32_t u[4]; short8 v; } fu;
      fu.u[0] = frP[ks][0]; fu.u[1] = frP[ks][1];
      fu.u[2] = frP[ks][2]; fu.u[3] = frP[ks][3];
#pragma unroll
      for (int j = 0; j < 4; ++j) {
        const short8 vf =
            *(const short8*)(Vc + (j * 16 + il) * 64 + ((((ks << 2) + g) ^ (il & 7)) << 3));
        acco[j] = __builtin_amdgcn_mfma_f32_16x16x32_bf16(fu.v, vf, acco[j], 0, 0, 0);
      }
      acc_l = __builtin_amdgcn_mfma_f32_16x16x32_bf16(fu.v, ones.v, acc_l, 0, 0, 0);
    }
  };

  auto softmax_pack = [&]() {
    // per-lane max of 16 relative scores (max3-friendly triples)
    float pmax = fmaxf(fmaxf(fmaxf(accs[0][0], accs[0][1]), accs[0][2]), accs[0][3]);
    pmax = fmaxf(pmax, fmaxf(fmaxf(accs[1][0], accs[1][1]), fmaxf(accs[1][2], accs[1][3])));
    pmax = fmaxf(pmax, fmaxf(fmaxf(accs[2][0], accs[2][1]), fmaxf(accs[2][2], accs[2][3])));
    pmax = fmaxf(pmax, fmaxf(fmaxf(accs[3][0], accs[3][1]), fmaxf(accs[3][2], accs[3][3])));

    uint32_t pk[4][2];
    if (!__all(pmax <= 8.0f)) {
      float mx = pmax;
#pragma unroll
      for (int off = 1; off < 64; off <<= 1) mx = fmaxf(mx, __shfl_xor(mx, off));
      const float alpha = __builtin_amdgcn_exp2f(-mx);
      m_run += mx;
#pragma unroll
      for (int j = 0; j < 4; ++j) acco[j] = acco[j] * alpha;
      acc_l = acc_l * alpha;
#pragma unroll
      for (int i = 0; i < 4; ++i) {
        const float p0 = __builtin_amdgcn_exp2f(accs[i][0] - mx);
        const float p1 = __builtin_amdgcn_exp2f(accs[i][1] - mx);
        const float p2 = __builtin_amdgcn_exp2f(accs[i][2] - mx);
        const float p3 = __builtin_amdgcn_exp2f(accs[i][3] - mx);
        asm("v_cvt_pk_bf16_f32 %0, %1, %2" : "=v"(pk[i][0]) : "v"(p0), "v"(p1));
        asm("v_cvt_pk_bf16_f32 %0, %1, %2" : "=v"(pk[i][1]) : "v"(p2), "v"(p3));
      }
    } else {
#pragma unroll
      for (int i = 0; i < 4; ++i) {
        const float p0 = __builtin_amdgcn_exp2f(accs[i][0]);
        const float p1 = __builtin_amdgcn_exp2f(accs[i][1]);
        const float p2 = __builtin_amdgcn_exp2f(accs[i][2]);
        const float p3 = __builtin_amdgcn_exp2f(accs[i][3]);
        asm("v_cvt_pk_bf16_f32 %0, %1, %2" : "=v"(pk[i][0]) : "v"(p0), "v"(p1));
        asm("v_cvt_pk_bf16_f32 %0, %1, %2" : "=v"(pk[i][1]) : "v"(p2), "v"(p3));
      }
    }
    // redistribute to PV A-fragment layout
#pragma unroll
    for (int ks = 0; ks < 2; ++ks) {
#pragma unroll
      for (int hh = 0; hh < 2; ++hh) {
        uint32_t a = pk[2 * ks][hh], bq = pk[2 * ks + 1][hh];
        asm("v_permlane32_swap_b32 %0, %1" : "+v"(a), "+v"(bq));
        asm("v_permlane16_swap_b32 %0, %1" : "+v"(a), "+v"(bq));
        frP[ks][hh] = a;
        frP[ks][2 + hh] = bq;
      }
    }
  };

  // ---- prologue: tile 0
  stage(0, 0);
  __syncthreads();           // drain tile-0 loads
  stage(1, 64);              // tile 1 into b1 (no readers yet)
  __builtin_amdgcn_s_setprio(1);
  qk_phase(0);
  __builtin_amdgcn_s_setprio(0);
  softmax_pack();            // P(0) -> frP

  const int NT = Tt / 64;
  for (int t = 1; t < NT; ++t) {
    const int cb = t & 1, pb = cb ^ 1;
    __syncthreads();         // B1: drains stage(t); all waves past PV(t-2)
    __builtin_amdgcn_s_setprio(1);
    qk_phase(cb);            // QK(t)   (accs)
    pv_phase(pb);            // PV(t-1) (frP) — independent, fills MFMA pipe
    __builtin_amdgcn_s_setprio(0);
    __syncthreads();         // B2: all waves done reading b[pb]
    if (t + 1 < NT) stage(pb, (t + 1) * 64);
    softmax_pack();          // P(t) -> frP; covers stage latency
  }
  // final PV for tile NT-1 (buffer (NT-1)&1 = 1, still valid)
  __builtin_amdgcn_s_setprio(1);
  pv_phase(1);
  __builtin_amdgcn_s_setprio(0);

  // epilogue
#pragma unroll
  for (int r = 0; r < 4; ++r) {
    const float li = 1.f / acc_l[r];
    const int tq = q0 + w * 16 + 4 * g + r;
    unsigned short* d0 = attnoT + ((size_t)b * Tt + tq) * Cc + h * 64 + il;
#pragma unroll
    for (int j = 0; j < 4; ++j) d0[j * 16] = f2bf(acco[j][r] * li);
  }
}

// ---------------------------------------------------------------------------
extern "C" void kernel_launch(void* const* d_in, const int* in_sizes, int n_in,
                              void* d_out, int out_size, void* d_ws, size_t ws_size,
                              hipStream_t stream) {
  const float* x = (const float*)d_in[0];
  const float* gamma = (const float*)d_in[1];
  const float* beta = (const float*)d_in[2];
  const float* w_qkv = (const float*)d_in[3];
  const float* b_qkv = (const float*)d_in[4];
  const float* w_proj = (const float*)d_in[5];
  const float* b_proj = (const float*)d_in[6];
  float* out = (float*)d_out;

  char* p = (char*)d_ws;
  float* stats = (float*)p;                  p += 256 * sizeof(float);
  unsigned short* hT = (unsigned short*)p;   p += (size_t)Bb * Tt * Cc * 2;
  unsigned short* wq = (unsigned short*)p;   p += (size_t)3 * Cc * Cc * 2;
  unsigned short* wp = (unsigned short*)p;   p += (size_t)Cc * Cc * 2;
  unsigned short* qkvc = (unsigned short*)p; p += (size_t)Bb * 3 * Cc * Tt * 2;
  unsigned short* qkt = (unsigned short*)p;  p += (size_t)Bb * Hh * 2 * Tt * 64 * 2;
  unsigned short* attnoT = (unsigned short*)p;

  const int n4q = 3 * Cc * Cc / 4, n4p = Cc * Cc / 4;

  gn_stats<<<dim3(Bb * 32), 256, 0, stream>>>(x, stats);
  norm_trans<<<dim3(Tt / 64, Cc / 64, Bb), 256, 0, stream>>>(x, stats, gamma, beta, hT);
  cvt_bf16_2<<<dim3((n4q + n4p + 255) / 256), 256, 0, stream>>>(w_qkv, wq, n4q, w_proj, wp, n4p);
  gemm_mfma<0, 128><<<dim3(Tt / 128, (3 * Cc) / 128, Bb), 256, 0, stream>>>(
      wq, hT, b_qkv, nullptr, qkvc, nullptr, qkt, 3 * Cc);
  attn_mfma5<<<dim3(1024), 256, 0, stream>>>(qkt, qkvc, attnoT);
  gemm_mfma<1, 64><<<dim3(Tt / 128, Cc / 64, Bb), 256, 0, stream>>>(
      wp, attnoT, b_proj, x, nullptr, out, nullptr, Cc);
}